// Round 4
// baseline (158.896 us; speedup 1.0000x reference)
//
#include <hip/hip_runtime.h>
#include <stdint.h>

#define NPRED 2048
#define MT    512
#define BLK   256
#define NCAND 512
#define REC   2176   // per-batch ws record: srt[512]u16 | pairs[512]u16 | meta[8]i32

#define M_NPOS  0
#define M_NT    1
#define M_K     2
#define M_FIRST 3
#define M_THRHI 4
#define M_THRLO 5

template<int C>
__device__ __forceinline__ float dppminf(float v) {
  int o = __builtin_amdgcn_update_dpp(__float_as_int(v), __float_as_int(v), C, 0xF, 0xF, false);
  return fminf(v, __int_as_float(o));
}
template<int C>
__device__ __forceinline__ uint32_t dppminu(uint32_t v) {
  uint32_t o = (uint32_t)__builtin_amdgcn_update_dpp((int)v, (int)v, C, 0xF, 0xF, false);
  return v < o ? v : o;
}
__device__ __forceinline__ float wave_min_f32_l63(float v) {
  v = dppminf<0x111>(v); v = dppminf<0x112>(v); v = dppminf<0x114>(v);
  v = dppminf<0x118>(v); v = dppminf<0x142>(v); v = dppminf<0x143>(v);
  return __int_as_float(__builtin_amdgcn_readlane(__float_as_int(v), 63));
}
__device__ __forceinline__ uint32_t wave_min_u32_l63(uint32_t v) {
  v = dppminu<0x111>(v); v = dppminu<0x112>(v); v = dppminu<0x114>(v);
  v = dppminu<0x118>(v); v = dppminu<0x142>(v); v = dppminu<0x143>(v);
  return (uint32_t)__builtin_amdgcn_readlane((int)v, 63);
}

// Exact argmin over 512 targets (8/lane), lowest-index tie-break.
__device__ __forceinline__ int argmin_pred(const float* txr, const float* tyr,
                                           uint32_t okm, float x, float y,
                                           uint32_t lane8) {
  const float INF = __builtin_inff();
  float d[8];
#pragma unroll
  for (int j = 0; j < 8; ++j) {
    float dx = __fsub_rn(txr[j], x);
    float dy = __fsub_rn(tyr[j], y);
    float d2 = __fadd_rn(__fmul_rn(dx, dx), __fmul_rn(dy, dy));
    d[j] = ((okm >> j) & 1u) ? d2 : INF;
  }
  float l1 = fminf(d[0], d[1]), l2 = fminf(d[2], d[3]);
  float l3 = fminf(d[4], d[5]), l4 = fminf(d[6], d[7]);
  float lmin = fminf(fminf(l1, l2), fminf(l3, l4));
  float g = wave_min_f32_l63(lmin);
  int jb = 7;
#pragma unroll
  for (int j = 6; j >= 0; --j) jb = (d[j] == g) ? j : jb;
  uint32_t cnd = (lmin == g) ? (lane8 | (uint32_t)jb) : 0x7FFFFFFFu;
  return (int)wave_min_u32_l63(cnd);
}

// ---------------- K1: select + rank-sort + prob loss ----------------
__global__ __launch_bounds__(BLK) void prep_kernel(const float* __restrict__ preds,
                                                   const float* __restrict__ targets,
                                                   uint8_t* __restrict__ recs,
                                                   double* __restrict__ acc) {
  const int b = blockIdx.x;
  const float* __restrict__ P = preds   + (size_t)b * NPRED * 5;
  const float* __restrict__ T = targets + (size_t)b * MT * 5;
  uint16_t* __restrict__ srt = (uint16_t*)(recs + (size_t)b * REC);
  int* __restrict__ meta = (int*)(recs + (size_t)b * REC + 2048);

  __shared__ uint64_t keys[NPRED];   // 16 KB
  __shared__ uint64_t cand[NCAND];   // 4 KB
  __shared__ int hist[256];
  __shared__ int s_npos, s_nt, s_B, s_ncand;
  __shared__ uint64_t s_thr;
  __shared__ double red[BLK];

  const int tid = threadIdx.x;
  if (tid == 0) { s_npos = 0; s_nt = 0; s_B = 0; s_ncand = 0; s_thr = 0ull; }
  hist[tid] = 0;
  __syncthreads();

  int cpos = 0;
  for (int i = tid; i < NPRED; i += BLK) {
    float c = P[i * 5 + 0];
    cpos += (c > 0.5f) ? 1 : 0;
    uint32_t cb = __float_as_uint(c);
    keys[i] = ((uint64_t)(~cb) << 32) | (uint32_t)i;
    if (cb >= 0x3F000000u && cb < 0x3F800000u)
      atomicAdd(&hist[(cb >> 15) & 0xFF], 1);
  }
  atomicAdd(&s_npos, cpos);

  int ct = 0;
  for (int m = tid; m < MT; m += BLK) ct += (T[m * 5 + 0] == 1.0f) ? 1 : 0;
  atomicAdd(&s_nt, ct);
  __syncthreads();
  const int n_pos = s_npos;
  const int n_targs = s_nt;

  // wave0: suffix-scan histogram -> cutoff bucket B
  if (tid < 64) {
    const int lane = tid;
    int4 h4 = *reinterpret_cast<const int4*>(&hist[lane * 4]);
    int t = h4.x + h4.y + h4.z + h4.w;
    int S = t;
#pragma unroll
    for (int off = 1; off < 64; off <<= 1) {
      int o = __shfl_down(S, off);
      if (lane + off < 64) S += o;
    }
    int Snext = S - t;
    int s3 = h4.w + Snext;
    int s2 = h4.z + s3;
    int s1 = h4.y + s2;
    int s0 = h4.x + s1;
    int localB = -1;
    if      (s3 >= n_targs) localB = lane * 4 + 3;
    else if (s2 >= n_targs) localB = lane * 4 + 2;
    else if (s1 >= n_targs) localB = lane * 4 + 1;
    else if (s0 >= n_targs) localB = lane * 4 + 0;
    uint64_t q = __ballot(localB >= 0);
    if (q) {
      int hl = 63 - __clzll((long long)q);
      int B = __builtin_amdgcn_readlane(localB, hl);
      if (lane == 0) s_B = B;
    }
  }
  // zero-fill srt pads (before barrier that precedes rank scatter)
  for (int i = tid; i < NCAND; i += BLK) srt[i] = 0;
  __syncthreads();
  const int B = s_B;

  // gather candidates (bucket >= B)
  for (int i = tid; i < NPRED; i += BLK) {
    uint64_t k = keys[i];
    uint32_t cb = ~(uint32_t)(k >> 32);
    if (cb >= 0x3F000000u && cb < 0x3F800000u && (int)((cb >> 15) & 0xFF) >= B) {
      int slot = atomicAdd(&s_ncand, 1);
      if (slot < NCAND) cand[slot] = k;
    }
  }
  __syncthreads();
  const int ncand = min(s_ncand, NCAND);

  // rank-sort: rank = # smaller keys; scatter pred index by rank
  {
    uint64_t ka = (tid < ncand) ? cand[tid] : ~0ull;
    uint64_t kb = (tid + BLK < ncand) ? cand[tid + BLK] : ~0ull;
    int ra = 0, rb = 0;
    for (int j = 0; j < ncand; ++j) {
      uint64_t kj = cand[j];
      ra += (kj < ka) ? 1 : 0;
      rb += (kj < kb) ? 1 : 0;
    }
    if (tid < ncand) {
      srt[ra] = (uint16_t)(ka & 0xFFFFu);
      if (ra == n_targs - 1) s_thr = ka;
    }
    if (tid + BLK < ncand) {
      srt[rb] = (uint16_t)(kb & 0xFFFFu);
      if (rb == n_targs - 1) s_thr = kb;
    }
  }
  __syncthreads();
  const uint64_t thr = s_thr;

  // prob loss: t = (key <= thr)
  float accp = 0.f;
  for (int i = tid; i < NPRED; i += BLK) {
    uint64_t k = keys[i];
    float p = __uint_as_float(~(uint32_t)(k >> 32));
    accp += (k <= thr) ? -fmaxf(logf(p), -100.0f)
                       : -fmaxf(log1pf(-p), -100.0f);
  }
  red[tid] = (double)accp;
  __syncthreads();
  for (int s = BLK / 2; s > 0; s >>= 1) {
    if (tid < s) red[tid] += red[tid + s];
    __syncthreads();
  }
  if (tid == 0) {
    atomicAdd(&acc[4], red[0]);
    meta[M_NPOS] = n_pos;
    meta[M_NT]   = n_targs;
    meta[M_K]    = min(n_pos, n_targs);
    meta[M_THRHI] = (int)(thr >> 32);
    meta[M_THRLO] = (int)(thr & 0xFFFFFFFFu);
  }
}

// ---------------- K2: serial greedy match (one wave per batch) ----------------
__global__ __launch_bounds__(64) void match_kernel(const float* __restrict__ preds,
                                                   const float* __restrict__ targets,
                                                   uint8_t* __restrict__ recs) {
  const int b = blockIdx.x;
  const int lane = threadIdx.x;
  const float* __restrict__ P = preds   + (size_t)b * NPRED * 5;
  const float* __restrict__ T = targets + (size_t)b * MT * 5;
  uint16_t* __restrict__ srt = (uint16_t*)(recs + (size_t)b * REC);
  uint16_t* __restrict__ prs = (uint16_t*)(recs + (size_t)b * REC + 1024);
  int* __restrict__ meta = (int*)(recs + (size_t)b * REC + 2048);
  const int K = meta[M_K];

  __shared__ float spx[516], spy[516];
  __shared__ uint16_t plds[512];

  float txr[8], tyr[8];
  uint32_t okm = 0;
#pragma unroll
  for (int j = 0; j < 8; ++j) {
    int t = lane * 8 + j;
    float c = T[t * 5 + 0];
    txr[j] = T[t * 5 + 1];
    tyr[j] = T[t * 5 + 2];
    okm |= (c == 1.0f) ? (1u << j) : 0u;
  }
  for (int i = lane; i < 516; i += 64) { spx[i] = 0.f; spy[i] = 0.f; }
  __syncthreads();
  for (int i = lane; i < K; i += 64) {
    int pi = srt[i];
    spx[i] = P[pi * 5 + 1];
    spy[i] = P[pi * 5 + 2];
  }
  __syncthreads();

  const uint32_t lane8 = (uint32_t)(lane << 3);
  float x = spx[0], y = spy[0];
  for (int i = 0; i < K; ++i) {
    float xn = spx[i + 1], yn = spy[i + 1];
    int m = argmin_pred(txr, tyr, okm, x, y, lane8);
    okm &= ~(((m >> 3) == lane) ? (1u << (m & 7)) : 0u);
    if (lane == 0) plds[i] = (uint16_t)m;
    x = xn; y = yn;
  }
  uint32_t fi = okm ? (uint32_t)(lane * 8 + __ffs(okm) - 1) : 0xFFFFFFFFu;
  fi = wave_min_u32_l63(fi);
  if (lane == 0) meta[M_FIRST] = (fi < MT) ? (int)fi : 0;
  __syncthreads();
  for (int i = lane; i < K; i += 64) prs[i] = plds[i];
}

// ---------------- K3: deferred MSE + case_first ----------------
__global__ __launch_bounds__(BLK) void mse_kernel(const float* __restrict__ preds,
                                                  const float* __restrict__ targets,
                                                  const uint8_t* __restrict__ recs,
                                                  double* __restrict__ acc) {
  const int b = blockIdx.x;
  const int tid = threadIdx.x;
  const float* __restrict__ P = preds   + (size_t)b * NPRED * 5;
  const float* __restrict__ T = targets + (size_t)b * MT * 5;
  const uint16_t* __restrict__ srt = (const uint16_t*)(recs + (size_t)b * REC);
  const uint16_t* __restrict__ prs = (const uint16_t*)(recs + (size_t)b * REC + 1024);
  const int* __restrict__ meta = (const int*)(recs + (size_t)b * REC + 2048);
  const int n_pos = meta[M_NPOS], n_targs = meta[M_NT];
  const int K = meta[M_K], first = meta[M_FIRST];

  __shared__ double red[4][BLK];
  float ax = 0.f, ay = 0.f, aa = 0.f, ab = 0.f;

  for (int r = tid; r < K; r += BLK) {
    int m = prs[r];
    int pi = srt[r];
    float dx = __fsub_rn(P[pi * 5 + 1], T[m * 5 + 1]);
    float dy = __fsub_rn(P[pi * 5 + 2], T[m * 5 + 2]);
    float da = __fsub_rn(P[pi * 5 + 3], T[m * 5 + 3]);
    float db = __fsub_rn(P[pi * 5 + 4], T[m * 5 + 4]);
    ax += __fmul_rn(dx, dx);
    ay += __fmul_rn(dy, dy);
    aa += __fmul_rn(da, da);
    ab += __fmul_rn(db, db);
  }
  if (n_pos < n_targs) {
    float fx = T[first * 5 + 1], fy = T[first * 5 + 2];
    float fa = T[first * 5 + 3], fb = T[first * 5 + 4];
    for (int r = n_pos + tid; r < n_targs; r += BLK) {
      int pi = srt[r];
      float dx = __fsub_rn(P[pi * 5 + 1], fx);
      float dy = __fsub_rn(P[pi * 5 + 2], fy);
      float da = __fsub_rn(P[pi * 5 + 3], fa);
      float db = __fsub_rn(P[pi * 5 + 4], fb);
      ax += __fmul_rn(dx, dx);
      ay += __fmul_rn(dy, dy);
      aa += __fmul_rn(da, da);
      ab += __fmul_rn(db, db);
    }
  }
  red[0][tid] = (double)ax;
  red[1][tid] = (double)ay;
  red[2][tid] = (double)aa;
  red[3][tid] = (double)ab;
  __syncthreads();
  for (int s = BLK / 2; s > 0; s >>= 1) {
    if (tid < s) {
#pragma unroll
      for (int c = 0; c < 4; ++c) red[c][tid] += red[c][tid + s];
    }
    __syncthreads();
  }
  if (tid == 0) {
#pragma unroll
    for (int c = 0; c < 4; ++c) atomicAdd(&acc[c], red[c][0]);
  }
}

__global__ void finalize_kernel(const double* __restrict__ acc,
                                float* __restrict__ out, double inv) {
  int c = threadIdx.x;
  if (c < 5) out[c] = (float)(acc[c] * inv);
}

extern "C" void kernel_launch(void* const* d_in, const int* in_sizes, int n_in,
                              void* d_out, int out_size, void* d_ws, size_t ws_size,
                              hipStream_t stream) {
  const float* preds = (const float*)d_in[0];
  const float* targets = (const float*)d_in[1];
  int B = in_sizes[0] / (NPRED * 5);

  double* acc = (double*)d_ws;
  uint8_t* recs = (uint8_t*)d_ws + 64;

  hipMemsetAsync(acc, 0, 5 * sizeof(double), stream);
  prep_kernel<<<B, BLK, 0, stream>>>(preds, targets, recs, acc);
  match_kernel<<<B, 64, 0, stream>>>(preds, targets, recs);
  mse_kernel<<<B, BLK, 0, stream>>>(preds, targets, recs, acc);
  finalize_kernel<<<1, 64, 0, stream>>>(acc, (float*)d_out,
                                        1.0 / ((double)B * NPRED));
}